// Round 12
// baseline (217.431 us; speedup 1.0000x reference)
//
#include <hip/hip_runtime.h>
#include <hip/hip_bf16.h>

// MHA forward: N=2, S=T=2048, E=1024, H=16, HD=64. All-bf16 MFMA pipeline.
// attn: 32x32x16 MFMA, S^T trick (P in registers), 8-wave blocks.
// vT stored t-permuted so register P is directly a PV A-operand.
// LDS XOR-chunk swizzle: slot (row,p) holds chunk p ^ (row&7).
// R1: attn32 prefetch pipeline (stage i+1 before compute i, 1 barrier/tile).
// R2 fix: no arrays of LDS pointers (hipcc addrspacecast static-init error).
// R4: exp2 builtin + v_cvt_pk_bf16_f32 packing; strength-reduced staging ptrs;
// gemmk/gemmo bijective XCD-chunk swizzle.
// R5 LESSON (regression, reverted): cross-iteration exp/PV(i-1)-under-QK(i)
// pipeline = T15 anti-pattern (m253): 48.1 -> 56.1 us. Do NOT re-introduce.
// R6: osum MFMA removed (denominator = f32 psum, shfl+LDS combine).
// R7: gemmo 128x128 tile rework. R8/R9: gemmk mode-0 LDS-transpose epilogue.
// R10: prefetch pipeline on both GEMMs (gemmk 48.9 -> <43; total -19 us).
// R11: attn REWAVE 2q-halves x 4t-quarters (kf/vf read once for 2 MFMAs;
// LDS-read pipe halves). FAILED launch-once-vs-graph: racey 2-phase combine.
// R12: combine hardened — explicit s_waitcnt lgkmcnt(0) + sched_barrier(0)
// at the end of each publish/reduce block before the __syncthreads, so each
// wave's ds_writes/reads are serviced before it arrives at the barrier
// (rule-#18 class hipcc fencing hole around divergent-if + s_barrier).
// NOTE: launch_bounds (512,2) NOT (512,4) — the latter caps VGPR at 64 and
// spills ~140 MB/launch to scratch (round-7 regression: WRITE_SIZE 144 MB).
typedef __bf16 bf16x8 __attribute__((ext_vector_type(8)));
typedef __bf16 bf16x4 __attribute__((ext_vector_type(4)));
typedef float  f32x4  __attribute__((ext_vector_type(4)));
typedef float  f32x16 __attribute__((ext_vector_type(16)));
typedef unsigned int u32x4 __attribute__((ext_vector_type(4)));

#define MFMA16(a, b, c) __builtin_amdgcn_mfma_f32_16x16x32_bf16((a), (b), (c), 0, 0, 0)
#define MFMA32(a, b, c) __builtin_amdgcn_mfma_f32_32x32x16_bf16((a), (b), (c), 0, 0, 0)
#define LGKM_FENCE() do { asm volatile("s_waitcnt lgkmcnt(0)" ::: "memory"); \
                          __builtin_amdgcn_sched_barrier(0); } while (0)

constexpr int SEQ = 2048, EMB = 1024, NHEAD = 16, HD = 64;
constexpr float SSCALE = 0.18033688f;  // (1/8) * log2(e)

__device__ __forceinline__ void glds16(const void* g, void* l) {
    __builtin_amdgcn_global_load_lds(
        (const __attribute__((address_space(1))) void*)g,
        (__attribute__((address_space(3))) void*)l, 16, 0, 0);
}

// ---------------------------------------------------------------------------
// prep: z<4 -> weight transpose+cast (z==0 pre-scaled by SSCALE);
//       z>=4 -> fp32->bf16 convert of query/key/value.
// ---------------------------------------------------------------------------
__global__ __launch_bounds__(256)
void prep(const float* __restrict__ W0, const float* __restrict__ W1,
          const float* __restrict__ W2, const float* __restrict__ W3,
          __bf16* __restrict__ T0, __bf16* __restrict__ T1,
          __bf16* __restrict__ T2, __bf16* __restrict__ T3,
          const float* __restrict__ X0, const float* __restrict__ X1,
          const float* __restrict__ X2, __bf16* __restrict__ Y0,
          __bf16* __restrict__ Y1, __bf16* __restrict__ Y2)
{
    __shared__ float tile[32][33];
    const int z = blockIdx.z;
    if (z < 4) {
        const float* W = (z==0) ? W0 : (z==1) ? W1 : (z==2) ? W2 : W3;
        __bf16*      T = (z==0) ? T0 : (z==1) ? T1 : (z==2) ? T2 : T3;
        const float s = (z == 0) ? SSCALE : 1.0f;
        const int kb = blockIdx.x * 32, nb = blockIdx.y * 32;
        const int c = threadIdx.x & 31, r0 = threadIdx.x >> 5;
#pragma unroll
        for (int i = 0; i < 4; ++i)
            tile[r0 + 8*i][c] = W[(size_t)(kb + r0 + 8*i)*1024 + nb + c];
        __syncthreads();
#pragma unroll
        for (int i = 0; i < 4; ++i)
            T[(size_t)(nb + r0 + 8*i)*1024 + kb + c] = (__bf16)(tile[c][r0 + 8*i] * s);
    } else {
        const float* X = (z==4) ? X0 : (z==5) ? X1 : X2;
        __bf16*      Y = (z==4) ? Y0 : (z==5) ? Y1 : Y2;
        const size_t base =
            ((size_t)(blockIdx.y * 32 + blockIdx.x) * 256 + threadIdx.x) * 16;
#pragma unroll
        for (int j = 0; j < 2; ++j) {
            const float4* s4 = (const float4*)(X + base + j*8);
            float4 f0 = s4[0], f1 = s4[1];
            bf16x8 v;
            v[0]=(__bf16)f0.x; v[1]=(__bf16)f0.y; v[2]=(__bf16)f0.z; v[3]=(__bf16)f0.w;
            v[4]=(__bf16)f1.x; v[5]=(__bf16)f1.y; v[6]=(__bf16)f1.z; v[7]=(__bf16)f1.w;
            *(bf16x8*)(Y + base + j*8) = v;
        }
    }
}

// ---------------------------------------------------------------------------
// 128x128 tile GEMM for QKV projections, R10 prefetch-pipelined K-loop.
// mode 0: C bf16 [nh][t][64]   (q / k); R8 LDS-transposed epilogue
// mode 1: C bf16 [nh][64][t]   (vT, t-PERMUTED: group-index low-2-bit swap)
// R4: XCD-chunk swizzle — 768 blocks, 8 XCDs, 96/XCD.
// LDS: A0|B0|A1|B1 = 4 x 16 KB = 64 KB -> 2 blocks/CU.
// ---------------------------------------------------------------------------
struct GArg { const __bf16* A; const __bf16* Bt; const float* bias; void* C;
              int mode; int kbase; int kcount; float bscale; };
struct GArgs3 { GArg a[3]; };

__global__ __launch_bounds__(256)
void gemmk(GArgs3 args)
{
    const int lin = blockIdx.x + (blockIdx.y << 5) + (blockIdx.z << 8);
    const int nid = (lin & 7) * 96 + (lin >> 3);   // bijective: 768 = 8*96
    const int gz = nid >> 8, rem = nid & 255;
    const int bm = rem >> 3, bn = rem & 7;
    const GArg g = args.a[gz];
    __shared__ __attribute__((aligned(16))) __bf16 sm[4*128*64];  // 64 KB
    const int tid = threadIdx.x, lane = tid & 63, wave = tid >> 6;
    const int wm = wave >> 1, wn = wave & 1;
    const int quad = lane >> 4, l16 = lane & 15;

    // Persistent staging pointers: 4 A-loads + 4 B-loads per thread.
    const __bf16* ap[4];
    const __bf16* bp[4];
#pragma unroll
    for (int j = 0; j < 4; ++j) {
        const int ci = j*256 + tid;
        const int row = ci >> 3, cg = ((ci & 7) ^ (row & 7)) * 8;
        ap[j] = g.A  + (size_t)(bm*128 + row)*1024 + g.kbase + cg;
        bp[j] = g.Bt + (size_t)(bn*128 + row)*1024 + g.kbase + cg;
    }

    // stage K-tile into buffer b; advance pointers by one K-step (64 elems)
    auto stage = [&](int b) {
        __bf16* Ad = sm + b * 16384;
        __bf16* Bd = Ad + 8192;
#pragma unroll
        for (int j = 0; j < 4; ++j) {
            glds16(ap[j], &Ad[(j*256 + wave*64)*8]);
            glds16(bp[j], &Bd[(j*256 + wave*64)*8]);
            ap[j] += 64; bp[j] += 64;
        }
    };

    f32x4 acc[4][4] = {};

    stage(0);
    int cur = 0;
    for (int kt = 0; kt < g.kcount; ++kt) {
        __syncthreads();                 // drains own vmcnt -> buf[cur] ready
        if (kt < g.kcount - 1) stage(cur ^ 1);
        const __bf16* As = sm + cur * 16384;
        const __bf16* Bs = As + 8192;
#pragma unroll
        for (int ks = 0; ks < 2; ++ks) {
            const int kc = ks*4 + quad;
            bf16x8 af[4], bfr[4];
#pragma unroll
            for (int mt = 0; mt < 4; ++mt) {
                const int ar = wm*64 + mt*16 + l16;
                af[mt] = *(const bf16x8*)&As[ar*64 + (kc ^ (ar & 7))*8];
            }
#pragma unroll
            for (int nt = 0; nt < 4; ++nt) {
                const int br = wn*64 + nt*16 + l16;
                bfr[nt] = *(const bf16x8*)&Bs[br*64 + (kc ^ (br & 7))*8];
            }
#pragma unroll
            for (int mt = 0; mt < 4; ++mt)
#pragma unroll
                for (int nt = 0; nt < 4; ++nt)
                    acc[mt][nt] = MFMA16(af[mt], bfr[nt], acc[mt][nt]);
        }
        cur ^= 1;
    }

    if (g.mode == 0) {
        // R8 epilogue: acc -> Cs (32 KB, XOR-chunk swizzle by m&7) -> coalesced.
        __syncthreads();                 // all LDS reads of last K-iter done
        __bf16* Cs = sm;                 // reuse buf0 region (128x128 = 32 KB)
#pragma unroll
        for (int nt = 0; nt < 4; ++nt) {
            const int n = wn*64 + nt*16 + l16;         // block-local col
            const float bvs = g.bias[bn*128 + n] * g.bscale;
#pragma unroll
            for (int mt = 0; mt < 4; ++mt) {
                const int mb = wm*64 + mt*16 + quad*4; // block-local row
                f32x4 v = acc[mt][nt];
#pragma unroll
                for (int r = 0; r < 4; ++r) {
                    const int m = mb + r;
                    Cs[m*128 + (((n >> 3) ^ (m & 7)) * 8) + (n & 7)] =
                        (__bf16)(v[r] + bvs);
                }
            }
        }
        __syncthreads();
        // 256 runs of 128 B (128 m-rows x 2 head-halves); 8 lanes/run; 8 passes.
        __bf16* C = (__bf16*)g.C;
        const int p8 = tid & 7;
#pragma unroll
        for (int ps = 0; ps < 8; ++ps) {
            const int run = ps * 32 + (tid >> 3);      // 0..255
            const int m = run >> 1, hh = run & 1;      // local row, head-half
            const int gm = bm*128 + m;
            const int nb = gm >> 11, s = gm & 2047;
            const int h = bn*2 + hh;
            bf16x8 val = *(const bf16x8*)&Cs[m*128 + (((hh*8 + p8) ^ (m & 7)) * 8)];
            *(bf16x8*)&C[(size_t)(nb*NHEAD + h)*(SEQ*HD) + (size_t)s*HD + p8*8] = val;
        }
    } else {
        // mode 1 (vT, t-permuted): direct bf16x4 stores (8 B, unchanged).
#pragma unroll
        for (int nt = 0; nt < 4; ++nt) {
            const int n = bn*128 + wn*64 + nt*16 + l16;
            const float bvs = (g.bias ? g.bias[n] : 0.f) * g.bscale;
#pragma unroll
            for (int mt = 0; mt < 4; ++mt) {
                const int mbase = bm*128 + wm*64 + mt*16 + quad*4;
                f32x4 v = acc[mt][nt];
                __bf16* C = (__bf16*)g.C;
                const int h = n >> 6, d = n & 63;
                const int nb = mbase >> 11, s = mbase & 2047;
                // t-permute: within each 32-block, swap low 2 bits of the
                // 4-group index (tg 1<->2, 5<->6).
                const int tg = (s >> 2) & 7;
                const int pg = (tg & 4) | ((tg & 1) << 1) | ((tg & 2) >> 1);
                const int sp = (s & ~31) | (pg << 2);
                bf16x4 o;
#pragma unroll
                for (int r = 0; r < 4; ++r) o[r] = (__bf16)(v[r] + bvs);
                *(bf16x4*)&C[(size_t)(nb*NHEAD + h)*(SEQ*HD) + (size_t)d*SEQ + sp] = o;
            }
        }
    }
}

// ---------------------------------------------------------------------------
// Out-projection GEMM: 128x128 tiles, R10 prefetch-pipelined K-loop (64 KB
// LDS double-buffer, 2 blocks/CU), 256 blocks, XCD-chunked. C fp32 + bias.
// ---------------------------------------------------------------------------
__global__ __launch_bounds__(256)
void gemmo(const __bf16* __restrict__ A, const __bf16* __restrict__ Bt,
           const float* __restrict__ bias, float* __restrict__ C)
{
    const int lin = blockIdx.x + (blockIdx.y << 5);
    const int nid = (lin & 7) * 32 + (lin >> 3);   // bijective: 256 = 8*32
    const int bm = nid >> 3, bn = nid & 7;
    __shared__ __attribute__((aligned(16))) __bf16 sm[4*128*64];  // 64 KB
    const int tid = threadIdx.x, lane = tid & 63, wave = tid >> 6;
    const int wm = wave >> 1, wn = wave & 1;
    const int quad = lane >> 4, l16 = lane & 15;

    const __bf16* ap[4];
    const __bf16* bp[4];
#pragma unroll
    for (int j = 0; j < 4; ++j) {
        const int ci = j*256 + tid;
        const int row = ci >> 3, cg = ((ci & 7) ^ (row & 7)) * 8;
        ap[j] = A  + (size_t)(bm*128 + row)*1024 + cg;
        bp[j] = Bt + (size_t)(bn*128 + row)*1024 + cg;
    }

    auto stage = [&](int b) {
        __bf16* Ad = sm + b * 16384;
        __bf16* Bd = Ad + 8192;
#pragma unroll
        for (int j = 0; j < 4; ++j) {
            glds16(ap[j], &Ad[(j*256 + wave*64)*8]);
            glds16(bp[j], &Bd[(j*256 + wave*64)*8]);
            ap[j] += 64; bp[j] += 64;
        }
    };

    f32x4 acc[4][4] = {};

    stage(0);
    int cur = 0;
    for (int kt = 0; kt < 16; ++kt) {
        __syncthreads();
        if (kt < 15) stage(cur ^ 1);
        const __bf16* As = sm + cur * 16384;
        const __bf16* Bs = As + 8192;
#pragma unroll
        for (int ks = 0; ks < 2; ++ks) {
            const int kc = ks*4 + quad;
            bf16x8 af[4], bfr[4];
#pragma unroll
            for (int mt = 0; mt < 4; ++mt) {
                const int ar = wm*64 + mt*16 + l16;
                af[mt] = *(const bf16x8*)&As[ar*64 + (kc ^ (ar & 7))*8];
            }
#pragma unroll
            for (int nt = 0; nt < 4; ++nt) {
                const int br = wn*64 + nt*16 + l16;
                bfr[nt] = *(const bf16x8*)&Bs[br*64 + (kc ^ (br & 7))*8];
            }
#pragma unroll
            for (int mt = 0; mt < 4; ++mt)
#pragma unroll
                for (int nt = 0; nt < 4; ++nt)
                    acc[mt][nt] = MFMA16(af[mt], bfr[nt], acc[mt][nt]);
        }
        cur ^= 1;
    }
    // Epilogue: C fp32 [4096][1024] + bias. col = l16-based n, rows quad*4+r.
#pragma unroll
    for (int nt = 0; nt < 4; ++nt) {
        const int n = bn*128 + wn*64 + nt*16 + l16;
        const float bv = bias[n];
#pragma unroll
        for (int mt = 0; mt < 4; ++mt) {
            const int mbase = bm*128 + wm*64 + mt*16 + quad*4;
            f32x4 v = acc[mt][nt];
#pragma unroll
            for (int r = 0; r < 4; ++r)
                C[(size_t)(mbase + r)*1024 + n] = v[r] + bv;
        }
    }
}

// ---------------------------------------------------------------------------
// Flash attention, 32x32x16 MFMA, register P, 8 waves (512 thr).
// R11 rewave: wave = (qh = wave>>2) q-half x (tq = wave&3) t-quarter.
// Each wave: 64 q-rows (2 x 32-q groups) x 32 t. kf/vf read ONCE per wave,
// used by 2 MFMAs (qg=0,1) -> LDS reads/wave/tile 16 -> 8, MFMA unchanged.
// R6 pipeline kept: 128-t tiles, K/V double-buffered (64 KB, 2 blocks/CU),
// stage(i+1) after barrier, 1 barrier/tile. f32 psum denominator per qg.
// Combine: 4-way over t-quarters, 2 qg-phases in dead K/V LDS (50.7 KB);
// R12: every publish/reduce block ends with LGKM_FENCE() so its LDS ops are
// serviced before the wave reaches the next barrier (race fix).
// q,k: [nh][t][64]; vT: [nh][64][t-permuted]; O: [N,S,E] bf16.
// ---------------------------------------------------------------------------
__global__ __launch_bounds__(512, 2)
void attn32(const __bf16* __restrict__ qg_, const __bf16* __restrict__ kg,
            const __bf16* __restrict__ vg, __bf16* __restrict__ Og)
{
    __shared__ __attribute__((aligned(16))) char smem[64*1024];
    // layout: K buf0 @0, K buf1 @16K, vT buf0 @32K, vT buf1 @48K (swizzled)
    float* Xch = (float*)smem;   // combine [2 qh][3 src][64 lane][33] = 50.7 KB

    const int tid = threadIdx.x, lane = tid & 63, wave = tid >> 6;
    const int tq = wave & 3, qh = wave >> 2;
    const int l32 = lane & 31, half = lane >> 5;
    const int nh = blockIdx.y;
    const int q0 = blockIdx.x * 128;
    const __bf16* qb = qg_ + (size_t)nh * (SEQ*HD);
    const __bf16* kb = kg + (size_t)nh * (SEQ*HD);
    const __bf16* vb = vg + (size_t)nh * (SEQ*HD);

    // Q B-frags, loop-invariant: B[k=ks*16+half*8+j][col=q] for 2 q-groups.
    bf16x8 qf[2][4];
#pragma unroll
    for (int qg = 0; qg < 2; ++qg)
#pragma unroll
        for (int ks = 0; ks < 4; ++ks)
            qf[qg][ks] = *(const bf16x8*)(qb +
                (size_t)(q0 + qh*64 + qg*32 + l32)*HD + ks*16 + half*8);

    f32x16 oacc[2][2] = {};          // [qg][dt]
    float psum0 = 0.0f, psum1 = 0.0f;

    // Persistent staging pointers (strength-reduced; advance per stage call).
    const int cK0 = tid, rK0 = cK0 >> 3;
    const int cK1 = 512 + tid, rK1 = cK1 >> 3;
    const __bf16* kp0 = kb + (size_t)rK0*HD + ((cK0 & 7) ^ (rK0 & 7)) * 8;
    const __bf16* kp1 = kb + (size_t)rK1*HD + ((cK1 & 7) ^ (rK1 & 7)) * 8;
    const int cV0 = tid, rV0 = cV0 >> 4, pV0 = cV0 & 15;
    const int cV1 = 512 + tid, rV1 = cV1 >> 4, pV1 = cV1 & 15;
    const __bf16* vp0 = vb + (size_t)rV0*SEQ + (((pV0 & ~7) | ((pV0 & 7) ^ (rV0 & 7))) * 8);
    const __bf16* vp1 = vb + (size_t)rV1*SEQ + (((pV1 & ~7) | ((pV1 & 7) ^ (rV1 & 7))) * 8);

    // stage next tile into buffer b; advances the 4 pointers by one tile
    auto stage = [&](int b) {
        char* Kd = smem + b * 16384;
        char* Vd = smem + 32768 + b * 16384;
        glds16(kp0, Kd + wave*1024);
        glds16(kp1, Kd + 8192 + wave*1024);
        glds16(vp0, Vd + wave*1024);
        glds16(vp1, Vd + 8192 + wave*1024);
        kp0 += 128*HD; kp1 += 128*HD;   // next 128 t-rows
        vp0 += 128;    vp1 += 128;      // vT: t advances by 128 within row
    };

    stage(0);
    int cur = 0;
    for (int it = 0; it < 16; ++it) {
        __syncthreads();                // drains own vmcnt -> buf[cur] ready
        if (it < 15) stage(cur ^ 1);

        const __bf16* Ks = (const __bf16*)(smem + cur * 16384);
        const __bf16* Vs = (const __bf16*)(smem + 32768 + cur * 16384);

        // S^T = K Q^T on this wave's 32-t quarter, both q-groups.
        f32x16 sc0 = {}, sc1 = {};
        const int kr = tq*32 + l32;
        __builtin_amdgcn_s_setprio(1);
#pragma unroll
        for (int ks = 0; ks < 4; ++ks) {
            const int c = ks*2 + half;
            bf16x8 kf = *(const bf16x8*)&Ks[kr*64 + ((c ^ (kr & 7))*8)];
            sc0 = MFMA32(kf, qf[0][ks], sc0);
            sc1 = MFMA32(kf, qf[1][ks], sc1);
        }
        __builtin_amdgcn_s_setprio(0);

        // P = exp2(S^T) in-register -> PV A-frags; O += P V; psum += e's.
#pragma unroll
        for (int sub = 0; sub < 2; ++sub) {
            float ea[8], eb[8];
#pragma unroll
            for (int j = 0; j < 8; ++j) {
                ea[j] = __builtin_amdgcn_exp2f(sc0[sub*8 + j]);
                eb[j] = __builtin_amdgcn_exp2f(sc1[sub*8 + j]);
            }
            psum0 += ((ea[0]+ea[1]) + (ea[2]+ea[3])) + ((ea[4]+ea[5]) + (ea[6]+ea[7]));
            psum1 += ((eb[0]+eb[1]) + (eb[2]+eb[3])) + ((eb[4]+eb[5]) + (eb[6]+eb[7]));
            u32x4 pka, pkb;
            asm("v_cvt_pk_bf16_f32 %0, %1, %2" : "=v"(pka.x) : "v"(ea[0]), "v"(ea[1]));
            asm("v_cvt_pk_bf16_f32 %0, %1, %2" : "=v"(pka.y) : "v"(ea[2]), "v"(ea[3]));
            asm("v_cvt_pk_bf16_f32 %0, %1, %2" : "=v"(pka.z) : "v"(ea[4]), "v"(ea[5]));
            asm("v_cvt_pk_bf16_f32 %0, %1, %2" : "=v"(pka.w) : "v"(ea[6]), "v"(ea[7]));
            asm("v_cvt_pk_bf16_f32 %0, %1, %2" : "=v"(pkb.x) : "v"(eb[0]), "v"(eb[1]));
            asm("v_cvt_pk_bf16_f32 %0, %1, %2" : "=v"(pkb.y) : "v"(eb[2]), "v"(eb[3]));
            asm("v_cvt_pk_bf16_f32 %0, %1, %2" : "=v"(pkb.z) : "v"(eb[4]), "v"(eb[5]));
            asm("v_cvt_pk_bf16_f32 %0, %1, %2" : "=v"(pkb.w) : "v"(eb[6]), "v"(eb[7]));
            const bf16x8 pf0 = __builtin_bit_cast(bf16x8, pka);
            const bf16x8 pf1 = __builtin_bit_cast(bf16x8, pkb);
            const int c2 = tq*4 + sub*2 + half;
            __builtin_amdgcn_s_setprio(1);
#pragma unroll
            for (int dt = 0; dt < 2; ++dt) {
                const int vr = dt*32 + l32;
                const int pos = (c2 & ~7) | ((c2 & 7) ^ (vr & 7));
                bf16x8 vf = *(const bf16x8*)&Vs[vr*128 + pos*8];
                oacc[0][dt] = MFMA32(pf0, vf, oacc[0][dt]);
                oacc[1][dt] = MFMA32(pf1, vf, oacc[1][dt]);
            }
            __builtin_amdgcn_s_setprio(0);
        }
        cur ^= 1;
    }

    // 4-way combine over t-quarters, 2 phases (qg=0 then qg=1).
    // R12: LGKM_FENCE at the end of every publish/reduce block.
    __syncthreads();
    if (tq != 0) {                       // phase A publish (qg=0)
        float* dst = &Xch[(((qh*3) + (tq-1))*64 + lane) * 33];
#pragma unroll
        for (int i = 0; i < 16; ++i) {
            dst[i]      = oacc[0][0][i];
            dst[16 + i] = oacc[0][1][i];
        }
        dst[32] = psum0;
        LGKM_FENCE();                    // writes serviced before barrier
    }
    __syncthreads();
    if (tq == 0) {                       // phase A reduce
#pragma unroll
        for (int s = 0; s < 3; ++s) {
            const float* src = &Xch[(((qh*3) + s)*64 + lane) * 33];
#pragma unroll
            for (int i = 0; i < 16; ++i) {
                oacc[0][0][i] += src[i];
                oacc[0][1][i] += src[16 + i];
            }
            psum0 += src[32];
        }
        LGKM_FENCE();                    // reads serviced before barrier
    }
    __syncthreads();
    if (tq != 0) {                       // phase B publish (qg=1)
        float* dst = &Xch[(((qh*3) + (tq-1))*64 + lane) * 33];
#pragma unroll
        for (int i = 0; i < 16; ++i) {
            dst[i]      = oacc[1][0][i];
            dst[16 + i] = oacc[1][1][i];
        }
        dst[32] = psum1;
        LGKM_FENCE();
    }
    __syncthreads();
    if (tq == 0) {                       // phase B reduce + write out
#pragma unroll
        for (int s = 0; s < 3; ++s) {
            const float* src = &Xch[(((qh*3) + s)*64 + lane) * 33];
#pragma unroll
            for (int i = 0; i < 16; ++i) {
                oacc[1][0][i] += src[i];
                oacc[1][1][i] += src[16 + i];
            }
            psum1 += src[32];
        }
        psum0 += __shfl(psum0, lane ^ 32);   // cross-half: full denom
        psum1 += __shfl(psum1, lane ^ 32);
        // broadcast denom[q] via LDS (512 B @ 60K, above the combine area)
        float* dl = (float*)(smem + 60*1024);
        if (half == 0) {
            dl[qh*64 + l32]      = psum0;
            dl[qh*64 + 32 + l32] = psum1;
        }
        LGKM_FENCE();                    // dl writes serviced before reads
        const int nb = nh >> 4, h = nh & 15;
#pragma unroll
        for (int qg = 0; qg < 2; ++qg)
#pragma unroll
            for (int reg = 0; reg < 16; ++reg) {
                const int row = (reg & 3) + 8*(reg >> 2) + 4*half;
                const int srow = q0 + qh*64 + qg*32 + row;
                const float inv = 1.0f / dl[qh*64 + qg*32 + row];
#pragma unroll
                for (int dt = 0; dt < 2; ++dt)
                    Og[(size_t)(nb*SEQ + srow)*EMB + h*HD + dt*32 + l32] =
                        (__bf16)(oacc[qg][dt][reg] * inv);
            }
    }
}

// ---------------------------------------------------------------------------
extern "C" void kernel_launch(void* const* d_in, const int* in_sizes, int n_in,
                              void* d_out, int out_size, void* d_ws, size_t ws_size,
                              hipStream_t stream)
{
    const float* query = (const float*)d_in[0];
    const float* key_  = (const float*)d_in[1];
    const float* value = (const float*)d_in[2];
    const float* Wq = (const float*)d_in[3];
    const float* bq = (const float*)d_in[4];
    const float* Wk = (const float*)d_in[5];
    const float* bk = (const float*)d_in[6];
    const float* Wv = (const float*)d_in[7];
    const float* bv = (const float*)d_in[8];
    const float* Wo = (const float*)d_in[9];
    const float* bo = (const float*)d_in[10];
    float* out = (float*)d_out;

    // d_out (16 MB) doubles as scratch for xq/xk until the out-projection.
    constexpr size_t SZW = 1024u*1024u;   // one weight matrix (elements)
    constexpr size_t SZX = 4096u*1024u;   // one activation tensor (elements)
    __bf16* ws  = (__bf16*)d_ws;
    __bf16* WqT = ws;
    __bf16* WkT = WqT + SZW;
    __bf16* WvT = WkT + SZW;
    __bf16* WoT = WvT + SZW;
    __bf16* xv  = WoT + SZW;
    __bf16* qh  = xv + SZX;
    __bf16* kh  = qh + SZX;
    __bf16* vTh = kh + SZX;              // ws total: 40 MiB
    __bf16* xq  = (__bf16*)d_out;        // first 8 MB of d_out
    __bf16* xk  = xq + SZX;              // second 8 MB of d_out
    __bf16* Oh  = xv;                    // xv dead after QKV GEMM

    // 1) weight transpose/cast (+Wq pre-scale) and activation fp32->bf16
    prep<<<dim3(32, 32, 7), 256, 0, stream>>>(Wq, Wk, Wv, Wo, WqT, WkT, WvT, WoT,
                                              query, key_, value, xq, xk, xv);
    // 2) fused QKV projections (single dispatch, 768 blocks, XCD-chunked)
    GArgs3 a;
    a.a[0] = { xq, WqT, bq, qh,  0, 0, 16, SSCALE };
    a.a[1] = { xk, WkT, bk, kh,  0, 0, 16, 1.0f };
    a.a[2] = { xv, WvT, bv, vTh, 1, 0, 16, 1.0f };
    gemmk<<<dim3(32, 8, 3), 256, 0, stream>>>(a);
    // 3) flash attention (32x32 MFMA, register P, rewaved 2q x 4t)
    attn32<<<dim3(16, 32), 512, 0, stream>>>(qh, kh, vTh, Oh);
    // 4) out-projection: 128x128 tiles, 256 blocks, XCD-chunked, pipelined
    gemmo<<<dim3(32, 8), 256, 0, stream>>>(Oh, WoT, bo, out);
}

// Round 13
// 206.155 us; speedup vs baseline: 1.0547x; 1.0547x over previous
//
#include <hip/hip_runtime.h>
#include <hip/hip_bf16.h>

// MHA forward: N=2, S=T=2048, E=1024, H=16, HD=64. All-bf16 MFMA pipeline.
// attn: 32x32x16 MFMA, S^T trick (P in registers), 8-wave blocks with T-split
// wave groups + exact partial combine (fixed-shift softmax => sums add).
// vT stored t-permuted so register P is directly a PV A-operand.
// LDS XOR-chunk swizzle: slot (row,p) holds chunk p ^ (row&7).
// R1: attn32 prefetch pipeline (stage i+1 before compute i, 1 barrier/tile).
// R2 fix: no arrays of LDS pointers (hipcc addrspacecast static-init error).
// R4: exp2 builtin + v_cvt_pk_bf16_f32 packing; strength-reduced staging ptrs;
// gemmk/gemmo bijective XCD-chunk swizzle.
// R5 LESSON (reverted): cross-iteration exp/PV(i-1)-under-QK(i) pipeline =
// T15 anti-pattern (m253): 48.1 -> 56.1 us. Do NOT re-introduce.
// R6: osum MFMA removed (denominator = f32 psum, shfl+LDS combine).
// R7: gemmo 128x128 tile rework. R8/R9: gemmk mode-0 LDS-transpose epilogue.
// R10: prefetch pipeline on both GEMMs (gemmk 48.9 -> <43; total -19 us).
// R11/R12 LESSON (reverted): 2q x 4t rewave halved LDS reads AND bank
// conflicts (4.19M -> 2.10M, mechanism confirmed) yet attn 43.4 -> 55.5 us,
// VGPR 60 -> 92 — attn is LATENCY/SYNC-bound, not LDS-throughput-bound.
// Structural attn rewaves have failed twice; do not re-attempt without a
// counted-vmcnt deep pipeline design.
// R13: attn reverted to exact R10 version (verified 43.4 us).
// NOTE: launch_bounds (512,2) NOT (512,4) — the latter caps VGPR at 64 and
// spills ~140 MB/launch to scratch (round-7 regression: WRITE_SIZE 144 MB).
typedef __bf16 bf16x8 __attribute__((ext_vector_type(8)));
typedef __bf16 bf16x4 __attribute__((ext_vector_type(4)));
typedef float  f32x4  __attribute__((ext_vector_type(4)));
typedef float  f32x16 __attribute__((ext_vector_type(16)));
typedef unsigned int u32x4 __attribute__((ext_vector_type(4)));

#define MFMA16(a, b, c) __builtin_amdgcn_mfma_f32_16x16x32_bf16((a), (b), (c), 0, 0, 0)
#define MFMA32(a, b, c) __builtin_amdgcn_mfma_f32_32x32x16_bf16((a), (b), (c), 0, 0, 0)

constexpr int SEQ = 2048, EMB = 1024, NHEAD = 16, HD = 64;
constexpr float SSCALE = 0.18033688f;  // (1/8) * log2(e)

__device__ __forceinline__ void glds16(const void* g, void* l) {
    __builtin_amdgcn_global_load_lds(
        (const __attribute__((address_space(1))) void*)g,
        (__attribute__((address_space(3))) void*)l, 16, 0, 0);
}

// ---------------------------------------------------------------------------
// prep: z<4 -> weight transpose+cast (z==0 pre-scaled by SSCALE);
//       z>=4 -> fp32->bf16 convert of query/key/value.
// ---------------------------------------------------------------------------
__global__ __launch_bounds__(256)
void prep(const float* __restrict__ W0, const float* __restrict__ W1,
          const float* __restrict__ W2, const float* __restrict__ W3,
          __bf16* __restrict__ T0, __bf16* __restrict__ T1,
          __bf16* __restrict__ T2, __bf16* __restrict__ T3,
          const float* __restrict__ X0, const float* __restrict__ X1,
          const float* __restrict__ X2, __bf16* __restrict__ Y0,
          __bf16* __restrict__ Y1, __bf16* __restrict__ Y2)
{
    __shared__ float tile[32][33];
    const int z = blockIdx.z;
    if (z < 4) {
        const float* W = (z==0) ? W0 : (z==1) ? W1 : (z==2) ? W2 : W3;
        __bf16*      T = (z==0) ? T0 : (z==1) ? T1 : (z==2) ? T2 : T3;
        const float s = (z == 0) ? SSCALE : 1.0f;
        const int kb = blockIdx.x * 32, nb = blockIdx.y * 32;
        const int c = threadIdx.x & 31, r0 = threadIdx.x >> 5;
#pragma unroll
        for (int i = 0; i < 4; ++i)
            tile[r0 + 8*i][c] = W[(size_t)(kb + r0 + 8*i)*1024 + nb + c];
        __syncthreads();
#pragma unroll
        for (int i = 0; i < 4; ++i)
            T[(size_t)(nb + r0 + 8*i)*1024 + kb + c] = (__bf16)(tile[c][r0 + 8*i] * s);
    } else {
        const float* X = (z==4) ? X0 : (z==5) ? X1 : X2;
        __bf16*      Y = (z==4) ? Y0 : (z==5) ? Y1 : Y2;
        const size_t base =
            ((size_t)(blockIdx.y * 32 + blockIdx.x) * 256 + threadIdx.x) * 16;
#pragma unroll
        for (int j = 0; j < 2; ++j) {
            const float4* s4 = (const float4*)(X + base + j*8);
            float4 f0 = s4[0], f1 = s4[1];
            bf16x8 v;
            v[0]=(__bf16)f0.x; v[1]=(__bf16)f0.y; v[2]=(__bf16)f0.z; v[3]=(__bf16)f0.w;
            v[4]=(__bf16)f1.x; v[5]=(__bf16)f1.y; v[6]=(__bf16)f1.z; v[7]=(__bf16)f1.w;
            *(bf16x8*)(Y + base + j*8) = v;
        }
    }
}

// ---------------------------------------------------------------------------
// 128x128 tile GEMM for QKV projections, R10 prefetch-pipelined K-loop.
// mode 0: C bf16 [nh][t][64]   (q / k); R8 LDS-transposed epilogue
// mode 1: C bf16 [nh][64][t]   (vT, t-PERMUTED: group-index low-2-bit swap)
// R4: XCD-chunk swizzle — 768 blocks, 8 XCDs, 96/XCD.
// LDS: A0|B0|A1|B1 = 4 x 16 KB = 64 KB -> 2 blocks/CU.
// ---------------------------------------------------------------------------
struct GArg { const __bf16* A; const __bf16* Bt; const float* bias; void* C;
              int mode; int kbase; int kcount; float bscale; };
struct GArgs3 { GArg a[3]; };

__global__ __launch_bounds__(256)
void gemmk(GArgs3 args)
{
    const int lin = blockIdx.x + (blockIdx.y << 5) + (blockIdx.z << 8);
    const int nid = (lin & 7) * 96 + (lin >> 3);   // bijective: 768 = 8*96
    const int gz = nid >> 8, rem = nid & 255;
    const int bm = rem >> 3, bn = rem & 7;
    const GArg g = args.a[gz];
    __shared__ __attribute__((aligned(16))) __bf16 sm[4*128*64];  // 64 KB
    const int tid = threadIdx.x, lane = tid & 63, wave = tid >> 6;
    const int wm = wave >> 1, wn = wave & 1;
    const int quad = lane >> 4, l16 = lane & 15;

    // Persistent staging pointers: 4 A-loads + 4 B-loads per thread.
    const __bf16* ap[4];
    const __bf16* bp[4];
#pragma unroll
    for (int j = 0; j < 4; ++j) {
        const int ci = j*256 + tid;
        const int row = ci >> 3, cg = ((ci & 7) ^ (row & 7)) * 8;
        ap[j] = g.A  + (size_t)(bm*128 + row)*1024 + g.kbase + cg;
        bp[j] = g.Bt + (size_t)(bn*128 + row)*1024 + g.kbase + cg;
    }

    // stage K-tile into buffer b; advance pointers by one K-step (64 elems)
    auto stage = [&](int b) {
        __bf16* Ad = sm + b * 16384;
        __bf16* Bd = Ad + 8192;
#pragma unroll
        for (int j = 0; j < 4; ++j) {
            glds16(ap[j], &Ad[(j*256 + wave*64)*8]);
            glds16(bp[j], &Bd[(j*256 + wave*64)*8]);
            ap[j] += 64; bp[j] += 64;
        }
    };

    f32x4 acc[4][4] = {};

    stage(0);
    int cur = 0;
    for (int kt = 0; kt < g.kcount; ++kt) {
        __syncthreads();                 // drains own vmcnt -> buf[cur] ready
        if (kt < g.kcount - 1) stage(cur ^ 1);
        const __bf16* As = sm + cur * 16384;
        const __bf16* Bs = As + 8192;
#pragma unroll
        for (int ks = 0; ks < 2; ++ks) {
            const int kc = ks*4 + quad;
            bf16x8 af[4], bfr[4];
#pragma unroll
            for (int mt = 0; mt < 4; ++mt) {
                const int ar = wm*64 + mt*16 + l16;
                af[mt] = *(const bf16x8*)&As[ar*64 + (kc ^ (ar & 7))*8];
            }
#pragma unroll
            for (int nt = 0; nt < 4; ++nt) {
                const int br = wn*64 + nt*16 + l16;
                bfr[nt] = *(const bf16x8*)&Bs[br*64 + (kc ^ (br & 7))*8];
            }
#pragma unroll
            for (int mt = 0; mt < 4; ++mt)
#pragma unroll
                for (int nt = 0; nt < 4; ++nt)
                    acc[mt][nt] = MFMA16(af[mt], bfr[nt], acc[mt][nt]);
        }
        cur ^= 1;
    }

    if (g.mode == 0) {
        // R8 epilogue: acc -> Cs (32 KB, XOR-chunk swizzle by m&7) -> coalesced.
        __syncthreads();                 // all LDS reads of last K-iter done
        __bf16* Cs = sm;                 // reuse buf0 region (128x128 = 32 KB)
#pragma unroll
        for (int nt = 0; nt < 4; ++nt) {
            const int n = wn*64 + nt*16 + l16;         // block-local col
            const float bvs = g.bias[bn*128 + n] * g.bscale;
#pragma unroll
            for (int mt = 0; mt < 4; ++mt) {
                const int mb = wm*64 + mt*16 + quad*4; // block-local row
                f32x4 v = acc[mt][nt];
#pragma unroll
                for (int r = 0; r < 4; ++r) {
                    const int m = mb + r;
                    Cs[m*128 + (((n >> 3) ^ (m & 7)) * 8) + (n & 7)] =
                        (__bf16)(v[r] + bvs);
                }
            }
        }
        __syncthreads();
        // 256 runs of 128 B (128 m-rows x 2 head-halves); 8 lanes/run; 8 passes.
        __bf16* C = (__bf16*)g.C;
        const int p8 = tid & 7;
#pragma unroll
        for (int ps = 0; ps < 8; ++ps) {
            const int run = ps * 32 + (tid >> 3);      // 0..255
            const int m = run >> 1, hh = run & 1;      // local row, head-half
            const int gm = bm*128 + m;
            const int nb = gm >> 11, s = gm & 2047;
            const int h = bn*2 + hh;
            bf16x8 val = *(const bf16x8*)&Cs[m*128 + (((hh*8 + p8) ^ (m & 7)) * 8)];
            *(bf16x8*)&C[(size_t)(nb*NHEAD + h)*(SEQ*HD) + (size_t)s*HD + p8*8] = val;
        }
    } else {
        // mode 1 (vT, t-permuted): direct bf16x4 stores (8 B, unchanged).
#pragma unroll
        for (int nt = 0; nt < 4; ++nt) {
            const int n = bn*128 + wn*64 + nt*16 + l16;
            const float bvs = (g.bias ? g.bias[n] : 0.f) * g.bscale;
#pragma unroll
            for (int mt = 0; mt < 4; ++mt) {
                const int mbase = bm*128 + wm*64 + mt*16 + quad*4;
                f32x4 v = acc[mt][nt];
                __bf16* C = (__bf16*)g.C;
                const int h = n >> 6, d = n & 63;
                const int nb = mbase >> 11, s = mbase & 2047;
                // t-permute: within each 32-block, swap low 2 bits of the
                // 4-group index (tg 1<->2, 5<->6).
                const int tg = (s >> 2) & 7;
                const int pg = (tg & 4) | ((tg & 1) << 1) | ((tg & 2) >> 1);
                const int sp = (s & ~31) | (pg << 2);
                bf16x4 o;
#pragma unroll
                for (int r = 0; r < 4; ++r) o[r] = (__bf16)(v[r] + bvs);
                *(bf16x4*)&C[(size_t)(nb*NHEAD + h)*(SEQ*HD) + (size_t)d*SEQ + sp] = o;
            }
        }
    }
}

// ---------------------------------------------------------------------------
// Out-projection GEMM: 128x128 tiles, R10 prefetch-pipelined K-loop (64 KB
// LDS double-buffer, 2 blocks/CU), 256 blocks, XCD-chunked. C fp32 + bias.
// ---------------------------------------------------------------------------
__global__ __launch_bounds__(256)
void gemmo(const __bf16* __restrict__ A, const __bf16* __restrict__ Bt,
           const float* __restrict__ bias, float* __restrict__ C)
{
    const int lin = blockIdx.x + (blockIdx.y << 5);
    const int nid = (lin & 7) * 32 + (lin >> 3);   // bijective: 256 = 8*32
    const int bm = nid >> 3, bn = nid & 7;
    __shared__ __attribute__((aligned(16))) __bf16 sm[4*128*64];  // 64 KB
    const int tid = threadIdx.x, lane = tid & 63, wave = tid >> 6;
    const int wm = wave >> 1, wn = wave & 1;
    const int quad = lane >> 4, l16 = lane & 15;

    const __bf16* ap[4];
    const __bf16* bp[4];
#pragma unroll
    for (int j = 0; j < 4; ++j) {
        const int ci = j*256 + tid;
        const int row = ci >> 3, cg = ((ci & 7) ^ (row & 7)) * 8;
        ap[j] = A  + (size_t)(bm*128 + row)*1024 + cg;
        bp[j] = Bt + (size_t)(bn*128 + row)*1024 + cg;
    }

    auto stage = [&](int b) {
        __bf16* Ad = sm + b * 16384;
        __bf16* Bd = Ad + 8192;
#pragma unroll
        for (int j = 0; j < 4; ++j) {
            glds16(ap[j], &Ad[(j*256 + wave*64)*8]);
            glds16(bp[j], &Bd[(j*256 + wave*64)*8]);
            ap[j] += 64; bp[j] += 64;
        }
    };

    f32x4 acc[4][4] = {};

    stage(0);
    int cur = 0;
    for (int kt = 0; kt < 16; ++kt) {
        __syncthreads();
        if (kt < 15) stage(cur ^ 1);
        const __bf16* As = sm + cur * 16384;
        const __bf16* Bs = As + 8192;
#pragma unroll
        for (int ks = 0; ks < 2; ++ks) {
            const int kc = ks*4 + quad;
            bf16x8 af[4], bfr[4];
#pragma unroll
            for (int mt = 0; mt < 4; ++mt) {
                const int ar = wm*64 + mt*16 + l16;
                af[mt] = *(const bf16x8*)&As[ar*64 + (kc ^ (ar & 7))*8];
            }
#pragma unroll
            for (int nt = 0; nt < 4; ++nt) {
                const int br = wn*64 + nt*16 + l16;
                bfr[nt] = *(const bf16x8*)&Bs[br*64 + (kc ^ (br & 7))*8];
            }
#pragma unroll
            for (int mt = 0; mt < 4; ++mt)
#pragma unroll
                for (int nt = 0; nt < 4; ++nt)
                    acc[mt][nt] = MFMA16(af[mt], bfr[nt], acc[mt][nt]);
        }
        cur ^= 1;
    }
    // Epilogue: C fp32 [4096][1024] + bias. col = l16-based n, rows quad*4+r.
#pragma unroll
    for (int nt = 0; nt < 4; ++nt) {
        const int n = bn*128 + wn*64 + nt*16 + l16;
        const float bv = bias[n];
#pragma unroll
        for (int mt = 0; mt < 4; ++mt) {
            const int mbase = bm*128 + wm*64 + mt*16 + quad*4;
            f32x4 v = acc[mt][nt];
#pragma unroll
            for (int r = 0; r < 4; ++r)
                C[(size_t)(mbase + r)*1024 + n] = v[r] + bv;
        }
    }
}

// ---------------------------------------------------------------------------
// Flash attention, 32x32x16 MFMA, register P, 8 waves (512 thr).
// R10/R6 structure (verified 43.4 us): 128-t tiles, K/V double-buffered
// (4x16KB = 64 KB, 2 blocks/CU), stage(i+1) issued right after the barrier,
// then QK(i) and exp/PV(i) from buf[cur]. Denominator: f32 thread-local sum
// of e-values (osum MFMA removed); combined via shfl(lane^32) + LDS.
// Wave group g = wave>>2 handles t-half g of each staged tile; both groups
// cover the same 128 Q-rows (w4 = wave&3, 32 rows each). Fixed-shift softmax
// => group partials combine by plain addition via LDS.
// q,k: [nh][t][64]; vT: [nh][64][t-permuted]; O: [N,S,E] bf16.
// ---------------------------------------------------------------------------
__global__ __launch_bounds__(512, 2)
void attn32(const __bf16* __restrict__ qg, const __bf16* __restrict__ kg,
            const __bf16* __restrict__ vg, __bf16* __restrict__ Og)
{
    __shared__ __attribute__((aligned(16))) char smem[64*1024];
    // layout: K buf0 @0, K buf1 @16K, vT buf0 @32K, vT buf1 @48K (swizzled)
    float* Xch = (float*)smem;               // combine area [4][64][33] (~34 KB)

    const int tid = threadIdx.x, lane = tid & 63, wave = tid >> 6;
    const int w4 = wave & 3, grp = wave >> 2;
    const int l32 = lane & 31, half = lane >> 5;
    const int nh = blockIdx.y;
    const int q0 = blockIdx.x * 128;
    const __bf16* qb = qg + (size_t)nh * (SEQ*HD);
    const __bf16* kb = kg + (size_t)nh * (SEQ*HD);
    const __bf16* vb = vg + (size_t)nh * (SEQ*HD);

    // Q B-frags from global, loop-invariant: B[k=ks*16+half*8+j][n=l32]
    bf16x8 qf[4];
#pragma unroll
    for (int ks = 0; ks < 4; ++ks)
        qf[ks] = *(const bf16x8*)(qb + (size_t)(q0 + w4*32 + l32)*HD + ks*16 + half*8);

    f32x16 oacc[2] = {};
    float psum = 0.0f;

    // Persistent staging pointers (strength-reduced; advance per stage call).
    const int cK0 = tid, rK0 = cK0 >> 3;
    const int cK1 = 512 + tid, rK1 = cK1 >> 3;
    const __bf16* kp0 = kb + (size_t)rK0*HD + ((cK0 & 7) ^ (rK0 & 7)) * 8;
    const __bf16* kp1 = kb + (size_t)rK1*HD + ((cK1 & 7) ^ (rK1 & 7)) * 8;
    const int cV0 = tid, rV0 = cV0 >> 4, pV0 = cV0 & 15;
    const int cV1 = 512 + tid, rV1 = cV1 >> 4, pV1 = cV1 & 15;
    const __bf16* vp0 = vb + (size_t)rV0*SEQ + (((pV0 & ~7) | ((pV0 & 7) ^ (rV0 & 7))) * 8);
    const __bf16* vp1 = vb + (size_t)rV1*SEQ + (((pV1 & ~7) | ((pV1 & 7) ^ (rV1 & 7))) * 8);

    // stage next tile into buffer b; advances the 4 pointers by one tile
    auto stage = [&](int b) {
        char* Kd = smem + b * 16384;
        char* Vd = smem + 32768 + b * 16384;
        glds16(kp0, Kd + wave*1024);
        glds16(kp1, Kd + 8192 + wave*1024);
        glds16(vp0, Vd + wave*1024);
        glds16(vp1, Vd + 8192 + wave*1024);
        kp0 += 128*HD; kp1 += 128*HD;   // next 128 t-rows
        vp0 += 128;    vp1 += 128;      // vT: t advances by 128 within row
    };

    stage(0);
    int cur = 0;
    for (int it = 0; it < 16; ++it) {
        __syncthreads();                // drains own vmcnt -> buf[cur] ready
        if (it < 15) stage(cur ^ 1);

        const __bf16* Ks = (const __bf16*)(smem + cur * 16384);
        const __bf16* Vs = (const __bf16*)(smem + 32768 + cur * 16384);

        // S^T = K Q^T on this group's 64-t half: lane = q-col, regs = t-rows.
        f32x16 sc[2] = {};
        __builtin_amdgcn_s_setprio(1);
#pragma unroll
        for (int ks = 0; ks < 4; ++ks) {
            const int c = ks*2 + half;
#pragma unroll
            for (int nt = 0; nt < 2; ++nt) {
                const int kr = grp*64 + nt*32 + l32;
                bf16x8 kf = *(const bf16x8*)&Ks[kr*64 + ((c ^ (kr & 7))*8)];
                sc[nt] = MFMA32(kf, qf[ks], sc[nt]);
            }
        }
        __builtin_amdgcn_s_setprio(0);

        // P = exp2(S^T) in-register -> PV A-frags; O += P V; psum += e's.
#pragma unroll
        for (int nt = 0; nt < 2; ++nt)
#pragma unroll
            for (int sub = 0; sub < 2; ++sub) {
                const float e0 = __builtin_amdgcn_exp2f(sc[nt][sub*8 + 0]);
                const float e1 = __builtin_amdgcn_exp2f(sc[nt][sub*8 + 1]);
                const float e2 = __builtin_amdgcn_exp2f(sc[nt][sub*8 + 2]);
                const float e3 = __builtin_amdgcn_exp2f(sc[nt][sub*8 + 3]);
                const float e4 = __builtin_amdgcn_exp2f(sc[nt][sub*8 + 4]);
                const float e5 = __builtin_amdgcn_exp2f(sc[nt][sub*8 + 5]);
                const float e6 = __builtin_amdgcn_exp2f(sc[nt][sub*8 + 6]);
                const float e7 = __builtin_amdgcn_exp2f(sc[nt][sub*8 + 7]);
                psum += ((e0 + e1) + (e2 + e3)) + ((e4 + e5) + (e6 + e7));
                u32x4 pk;
                asm("v_cvt_pk_bf16_f32 %0, %1, %2" : "=v"(pk.x) : "v"(e0), "v"(e1));
                asm("v_cvt_pk_bf16_f32 %0, %1, %2" : "=v"(pk.y) : "v"(e2), "v"(e3));
                asm("v_cvt_pk_bf16_f32 %0, %1, %2" : "=v"(pk.z) : "v"(e4), "v"(e5));
                asm("v_cvt_pk_bf16_f32 %0, %1, %2" : "=v"(pk.w) : "v"(e6), "v"(e7));
                const bf16x8 pf = __builtin_bit_cast(bf16x8, pk);
                const int c2 = grp*8 + (nt*2 + sub)*2 + half;
                __builtin_amdgcn_s_setprio(1);
#pragma unroll
                for (int dt = 0; dt < 2; ++dt) {
                    const int vr = dt*32 + l32;
                    const int pos = (c2 & ~7) | ((c2 & 7) ^ (vr & 7));
                    bf16x8 vf = *(const bf16x8*)&Vs[vr*128 + pos*8];
                    oacc[dt] = MFMA32(pf, vf, oacc[dt]);
                }
                __builtin_amdgcn_s_setprio(0);
            }
        cur ^= 1;
    }

    // Combine group partials: group 1 publishes, group 0 adds + writes out.
    __syncthreads();
    if (grp == 1) {
        float* dst = &Xch[((w4*64) + lane) * 33];
#pragma unroll
        for (int i = 0; i < 16; ++i) {
            dst[i]      = oacc[0][i];
            dst[16 + i] = oacc[1][i];
        }
        dst[32] = psum;
    }
    __syncthreads();
    if (grp == 0) {
        const float* src = &Xch[((w4*64) + lane) * 33];
#pragma unroll
        for (int i = 0; i < 16; ++i) {
            oacc[0][i] += src[i];
            oacc[1][i] += src[16 + i];
        }
        psum += src[32];
        psum += __shfl(psum, lane ^ 32);   // cross-half: full denom for q=l32
        // broadcast denom[q] via LDS (512 B @ 60K, above the combine area)
        float* dl = (float*)(smem + 60*1024);
        if (half == 0) dl[w4*32 + l32] = psum;   // same-wave RAW, lgkmcnt-ordered
        const int nb = nh >> 4, h = nh & 15;
#pragma unroll
        for (int reg = 0; reg < 16; ++reg) {
            const int row = (reg & 3) + 8*(reg >> 2) + 4*half;
            const int srow = q0 + w4*32 + row;
            const float inv = 1.0f / dl[w4*32 + row];
#pragma unroll
            for (int dt = 0; dt < 2; ++dt)
                Og[(size_t)(nb*SEQ + srow)*EMB + h*HD + dt*32 + l32] =
                    (__bf16)(oacc[dt][reg] * inv);
        }
    }
}

// ---------------------------------------------------------------------------
extern "C" void kernel_launch(void* const* d_in, const int* in_sizes, int n_in,
                              void* d_out, int out_size, void* d_ws, size_t ws_size,
                              hipStream_t stream)
{
    const float* query = (const float*)d_in[0];
    const float* key_  = (const float*)d_in[1];
    const float* value = (const float*)d_in[2];
    const float* Wq = (const float*)d_in[3];
    const float* bq = (const float*)d_in[4];
    const float* Wk = (const float*)d_in[5];
    const float* bk = (const float*)d_in[6];
    const float* Wv = (const float*)d_in[7];
    const float* bv = (const float*)d_in[8];
    const float* Wo = (const float*)d_in[9];
    const float* bo = (const float*)d_in[10];
    float* out = (float*)d_out;

    // d_out (16 MB) doubles as scratch for xq/xk until the out-projection.
    constexpr size_t SZW = 1024u*1024u;   // one weight matrix (elements)
    constexpr size_t SZX = 4096u*1024u;   // one activation tensor (elements)
    __bf16* ws  = (__bf16*)d_ws;
    __bf16* WqT = ws;
    __bf16* WkT = WqT + SZW;
    __bf16* WvT = WkT + SZW;
    __bf16* WoT = WvT + SZW;
    __bf16* xv  = WoT + SZW;
    __bf16* qh  = xv + SZX;
    __bf16* kh  = qh + SZX;
    __bf16* vTh = kh + SZX;              // ws total: 40 MiB
    __bf16* xq  = (__bf16*)d_out;        // first 8 MB of d_out
    __bf16* xk  = xq + SZX;              // second 8 MB of d_out
    __bf16* Oh  = xv;                    // xv dead after QKV GEMM

    // 1) weight transpose/cast (+Wq pre-scale) and activation fp32->bf16
    prep<<<dim3(32, 32, 7), 256, 0, stream>>>(Wq, Wk, Wv, Wo, WqT, WkT, WvT, WoT,
                                              query, key_, value, xq, xk, xv);
    // 2) fused QKV projections (single dispatch, 768 blocks, XCD-chunked)
    GArgs3 a;
    a.a[0] = { xq, WqT, bq, qh,  0, 0, 16, SSCALE };
    a.a[1] = { xk, WkT, bk, kh,  0, 0, 16, 1.0f };
    a.a[2] = { xv, WvT, bv, vTh, 1, 0, 16, 1.0f };
    gemmk<<<dim3(32, 8, 3), 256, 0, stream>>>(a);
    // 3) flash attention (32x32 MFMA, register P, prefetch-pipelined)
    attn32<<<dim3(16, 32), 512, 0, stream>>>(qh, kh, vTh, Oh);
    // 4) out-projection: 128x128 tiles, 256 blocks, XCD-chunked, pipelined
    gemmo<<<dim3(32, 8), 256, 0, stream>>>(Oh, WoT, bo, out);
}